// Round 8
// baseline (1116.413 us; speedup 1.0000x reference)
//
#include <hip/hip_runtime.h>
#include <hip/hip_bf16.h>
#include <cstdint>

#define NN 50000
#define NE 1600000
#define DV 256
#define DA 128

using floatx4 = __attribute__((ext_vector_type(4))) float;
using shortx8 = __attribute__((ext_vector_type(8))) short;

__device__ __forceinline__ unsigned short f2bf(float f) {
    union { float f; uint32_t u; } v; v.f = f;
    uint32_t u = v.u;
    uint32_t r = (u + 0x7FFFu + ((u >> 16) & 1u)) >> 16;   // RNE
    return (unsigned short)r;
}
__device__ __forceinline__ float bflo(uint32_t u) {
    union { uint32_t u; float f; } v; v.u = u << 16; return v.f;
}
__device__ __forceinline__ float bfhi(uint32_t u) {
    union { uint32_t u; float f; } v; v.u = u & 0xFFFF0000u; return v.f;
}
__device__ __forceinline__ shortx8 pack8(float4 a, float4 b) {
    shortx8 u;
    u[0] = (short)f2bf(a.x); u[1] = (short)f2bf(a.y);
    u[2] = (short)f2bf(a.z); u[3] = (short)f2bf(a.w);
    u[4] = (short)f2bf(b.x); u[5] = (short)f2bf(b.y);
    u[6] = (short)f2bf(b.z); u[7] = (short)f2bf(b.w);
    return u;
}

// ---------------- zero out + denom + cnt ----------------------------------
__global__ void init_zero(float4* __restrict__ out, float* __restrict__ denom,
                          int* __restrict__ cnt) {
    const float4 z = make_float4(0.f, 0.f, 0.f, 0.f);
    int i = blockIdx.x * blockDim.x + threadIdx.x;
    const int stride = gridDim.x * blockDim.x;
    for (int j = i; j < NN * 128 / 4; j += stride) out[j] = z;
    if (i < NN) { denom[i] = 0.f; cnt[i] = 0; }
}

// ---------------- cast weights fp32 -> bf16 -------------------------------
__global__ void cast_w_kernel(const float* __restrict__ wq, const float* __restrict__ wk,
                              const float* __restrict__ wv, unsigned short* __restrict__ out) {
    int i = blockIdx.x * blockDim.x + threadIdx.x;
    if (i < 32768)       out[i] = f2bf(wq[i]);
    else if (i < 65536)  out[i] = f2bf(wk[i - 32768]);
    else if (i < 81920)  out[i] = f2bf(wv[i - 65536]);
}

// ---------------- CSR build -----------------------------------------------
__global__ void hist_kernel(const int* __restrict__ ridx, int* __restrict__ cnt) {
    int e = blockIdx.x * blockDim.x + threadIdx.x;
    if (e < NE) atomicAdd(&cnt[ridx[e]], 1);
}

__global__ __launch_bounds__(1024)
void scan_kernel(const int* __restrict__ cnt, int* __restrict__ offs, int* __restrict__ offs2) {
    __shared__ int part[1024];
    const int tid = threadIdx.x;
    const int PER = (NN + 1023) / 1024;   // 49
    int base = tid * PER;
    int s = 0;
    for (int i = 0; i < PER; ++i) { int idx = base + i; if (idx < NN) s += cnt[idx]; }
    part[tid] = s;
    __syncthreads();
    for (int off = 1; off < 1024; off <<= 1) {
        int v = (tid >= off) ? part[tid - off] : 0;
        __syncthreads();
        part[tid] += v;
        __syncthreads();
    }
    int excl = (tid == 0) ? 0 : part[tid - 1];
    for (int i = 0; i < PER; ++i) {
        int idx = base + i;
        if (idx < NN) { offs[idx] = excl; offs2[idx] = excl; excl += cnt[idx]; }
    }
    if (tid == 0) offs2[NN] = NE;
}

// ---------------- fused Q,K projection: [NN,256] x [256,256]^T ------------
__global__ __launch_bounds__(256)
void proj_qk(const float* __restrict__ A, const unsigned short* __restrict__ Wst,
             const float* __restrict__ bq, const float* __restrict__ bk,
             unsigned short* __restrict__ qbf, unsigned short* __restrict__ kbf, int M) {
    __shared__ unsigned short Al[64 * 32];
    __shared__ unsigned short Bl[256 * 32];
    const int tid = threadIdx.x;
    const int lane = tid & 63, w = tid >> 6;
    const int m0 = blockIdx.x * 64;
    constexpr int K = 256;

    floatx4 acc[16];
#pragma unroll
    for (int i = 0; i < 16; ++i) acc[i] = (floatx4)0.0f;

    for (int kk = 0; kk < K; kk += 32) {
#pragma unroll
        for (int it = 0; it < 2; ++it) {
            int j = tid + it * 256;
            int row = j >> 3;
            int c4 = (j & 7) * 4;
            float4 f = make_float4(0.f, 0.f, 0.f, 0.f);
            int gm = m0 + row;
            if (gm < M) f = *reinterpret_cast<const float4*>(A + (size_t)gm * K + kk + c4);
            ushort4 u; u.x = f2bf(f.x); u.y = f2bf(f.y); u.z = f2bf(f.z); u.w = f2bf(f.w);
            *reinterpret_cast<ushort4*>(&Al[row * 32 + c4]) = u;
        }
#pragma unroll
        for (int it = 0; it < 4; ++it) {
            int j = tid + it * 256;
            int row = j >> 2;
            int c8 = (j & 3) * 8;
            uint4 v = *reinterpret_cast<const uint4*>(Wst + (size_t)row * K + kk + c8);
            *reinterpret_cast<uint4*>(&Bl[row * 32 + c8]) = v;
        }
        __syncthreads();
        shortx8 af = *reinterpret_cast<const shortx8*>(&Al[(w * 16 + (lane & 15)) * 32 + 8 * (lane >> 4)]);
#pragma unroll
        for (int nt = 0; nt < 16; ++nt) {
            shortx8 bf = *reinterpret_cast<const shortx8*>(&Bl[(nt * 16 + (lane & 15)) * 32 + 8 * (lane >> 4)]);
            acc[nt] = __builtin_amdgcn_mfma_f32_16x16x32_bf16(af, bf, acc[nt], 0, 0, 0);
        }
        __syncthreads();
    }
    const int col = lane & 15;
    const int rbase = m0 + w * 16 + 4 * (lane >> 4);
#pragma unroll
    for (int nt = 0; nt < 16; ++nt) {
        int gn = nt * 16 + col;
        bool isq = gn < 128;
        int oc = isq ? gn : gn - 128;
        float b = isq ? bq[oc] : bk[oc];
        unsigned short* O = isq ? qbf : kbf;
#pragma unroll
        for (int reg = 0; reg < 4; ++reg) {
            int gm = rbase + reg;
            if (gm < M) {
                float v = acc[nt][reg] + b;
                v = v > 0.f ? v : 0.01f * v;
                O[(size_t)gm * 128 + oc] = f2bf(v);
            }
        }
    }
}

// ---- pure permute: edges (fp32, natural) -> esort (bf16, receiver-sorted) -
// Max-TLP, no LDS, no barriers. Seq 819MB read, random 256B writes (410MB).
__global__ __launch_bounds__(512)
void edge_sort(const float* __restrict__ Ed, const int* __restrict__ ridx,
               const int* __restrict__ sidx, int* __restrict__ cursor,
               unsigned short* __restrict__ esort, int* __restrict__ ssort,
               int* __restrict__ rsort) {
    const int tid = threadIdx.x;
    const int lane = tid & 63;
    const size_t m0 = (size_t)blockIdx.x * 128;    // NE % 128 == 0
    const int erow = tid >> 2, qt = tid & 3;
    const size_t e = m0 + erow;

    const float* arow = Ed + e * 128 + qt * 32;    // this thread's 128B quarter
    float4 f[8];
#pragma unroll
    for (int i = 0; i < 8; ++i) f[i] = *reinterpret_cast<const float4*>(arow + i * 4);

    int pos = 0;
    if (qt == 0) {
        int r = ridx[e];
        pos = atomicAdd(&cursor[r], 1);
        ssort[pos] = sidx[e];
        rsort[pos] = r;
    }
    pos = __shfl(pos, lane & ~3);                  // broadcast within edge quad

    unsigned short* dst = esort + (size_t)pos * 128 + qt * 32;
#pragma unroll
    for (int i = 0; i < 4; ++i) {
        shortx8 u = pack8(f[2 * i], f[2 * i + 1]);
        *reinterpret_cast<shortx8*>(dst + i * 8) = u;
    }
}

// ---- fused sorted pass: seq bf16 edge reads, logits, V-GEMM, seg-reduce ---
// 500 blocks x 25 tiles of 128 edges. Wv staged once/block; A prefetched to
// regs one tile ahead; V never touches HBM.
// LDS map: [0,32768) Wv frags; [32768,65536) A frags / Vl alias;
// [65536,66048) pl; [66048,66560) rs_local; [66560,67072) segstart;
// [67072,67584) segnode; [67584,67600) masks; [67600,67604) nseg.
__global__ __launch_bounds__(512)
void fused_sorted(const unsigned short* __restrict__ esort, const unsigned short* __restrict__ wv_bf,
                  const float* __restrict__ bv,
                  const unsigned short* __restrict__ qbf, const unsigned short* __restrict__ kbf,
                  const int* __restrict__ ssort, const int* __restrict__ rsort,
                  float* __restrict__ out, float* __restrict__ denom, int tpb) {
    __shared__ __align__(16) char smem[67616];
    unsigned short* Vl = reinterpret_cast<unsigned short*>(smem + 32768);
    float* pl       = reinterpret_cast<float*>(smem + 65536);
    int*   rs_local = reinterpret_cast<int*>(smem + 66048);
    int*   segstart = reinterpret_cast<int*>(smem + 66560);
    int*   segnode  = reinterpret_cast<int*>(smem + 67072);
    unsigned long long* masks = reinterpret_cast<unsigned long long*>(smem + 67584);
    int* nseg_s = reinterpret_cast<int*>(smem + 67600);

    const int tid = threadIdx.x;
    const int lane = tid & 63, w = tid >> 6;
    const int erow = tid >> 2, qt = tid & 3;

    // ---- stage Wv fragment-linear once ----
#pragma unroll
    for (int it = 0; it < 4; ++it) {
        int s = tid + it * 512;
        int g = s >> 6, l = s & 63;
        int kt4 = g >> 3, nt = g & 7;
        uint4 v = *reinterpret_cast<const uint4*>(
            wv_bf + (size_t)(nt * 16 + (l & 15)) * 128 + kt4 * 32 + 8 * (l >> 4));
        *reinterpret_cast<uint4*>(smem + s * 16) = v;
    }

    const int t0 = blockIdx.x * tpb;
    // preload first tile's A quarter (64B = 4 uint4) into regs
    uint4 curA[4], nxtA[4];
    {
        const uint4* src = reinterpret_cast<const uint4*>(
            esort + ((size_t)t0 * 128 + erow) * 128 + qt * 32);
#pragma unroll
        for (int i = 0; i < 4; ++i) curA[i] = src[i];
    }
    __syncthreads();   // Wv staged

    const int colb = lane & 15;
    const int rquad = w * 16 + 4 * (lane >> 4);
    const int fragbase = 32768 + (((erow >> 4) * 4 + qt) << 10) + ((erow & 15) << 4);

    for (int tt = 0; tt < tpb; ++tt) {
        const size_t base = ((size_t)(t0 + tt)) * 128;

        // phase a: ds_write current A tile (fragment-linear)
#pragma unroll
        for (int g = 0; g < 4; ++g)
            *reinterpret_cast<uint4*>(smem + fragbase + g * 256) = curA[g];
        __syncthreads();   // B1

        // phase c1: prefetch next tile into regs (latency hides under MFMA)
        if (tt + 1 < tpb) {
            const uint4* src = reinterpret_cast<const uint4*>(
                esort + (base + 128 + erow) * 128 + qt * 32);
#pragma unroll
            for (int i = 0; i < 4; ++i) nxtA[i] = src[i];
        }

        // phase c2: receivers + logits (4 lanes per edge, 32 dims each)
        const int rN = rsort[base + erow];
        if (qt == 0) rs_local[erow] = rN;
        {
            const int sN = ssort[base + erow];
            const uint4* kp = reinterpret_cast<const uint4*>(kbf + (size_t)sN * 128 + qt * 32);
            const uint4* qp = reinterpret_cast<const uint4*>(qbf + (size_t)rN * 128 + qt * 32);
            float acq = 0.f;
#pragma unroll
            for (int i = 0; i < 4; ++i) {
                uint4 qa = qp[i], ka = kp[i];
                acq += bflo(qa.x) * bflo(ka.x) + bfhi(qa.x) * bfhi(ka.x);
                acq += bflo(qa.y) * bflo(ka.y) + bfhi(qa.y) * bfhi(ka.y);
                acq += bflo(qa.z) * bflo(ka.z) + bfhi(qa.z) * bfhi(ka.z);
                acq += bflo(qa.w) * bflo(ka.w) + bfhi(qa.w) * bfhi(ka.w);
            }
            acq += __shfl_xor(acq, 1);
            acq += __shfl_xor(acq, 2);
            if (qt == 0) pl[erow] = __expf(acq * 0.08838834764831845f);
        }

        // phase d: MFMA 4kt x 8nt
        floatx4 acc[8];
#pragma unroll
        for (int i = 0; i < 8; ++i) acc[i] = (floatx4)0.0f;
#pragma unroll
        for (int kt = 0; kt < 4; ++kt) {
            shortx8 af = *reinterpret_cast<const shortx8*>(
                smem + 32768 + ((w * 4 + kt) << 10) + (lane << 4));
#pragma unroll
            for (int nt = 0; nt < 8; ++nt) {
                shortx8 bfr = *reinterpret_cast<const shortx8*>(smem + (((kt * 8 + nt) * 64 + lane) << 4));
                acc[nt] = __builtin_amdgcn_mfma_f32_16x16x32_bf16(af, bfr, acc[nt], 0, 0, 0);
            }
        }
        __syncthreads();   // B2: MFMA done reading A; pl/rs_local complete

        // mask step 1 (waves 0,1)
        if (tid < 128) {
            bool flag = (tid == 0) || (rs_local[tid] != rs_local[tid - 1]);
            unsigned long long mk = __ballot(flag);
            if (lane == 0) masks[w] = mk;
        }
        // epilogue: bias + lrelu, scale by p -> Vl (aliases A region)
        float pe[4];
#pragma unroll
        for (int reg = 0; reg < 4; ++reg) pe[reg] = pl[rquad + reg];
#pragma unroll
        for (int nt = 0; nt < 8; ++nt) {
            float b = bv[nt * 16 + colb];
#pragma unroll
            for (int reg = 0; reg < 4; ++reg) {
                float v = acc[nt][reg] + b;
                v = v > 0.f ? v : 0.01f * v;
                Vl[(rquad + reg) * 128 + nt * 16 + colb] = f2bf(v * pe[reg]);
            }
        }
        __syncthreads();   // B3: Vl + masks visible

        // mask step 2
        if (tid < 128) {
            bool flag = (tid == 0) || (rs_local[tid] != rs_local[tid - 1]);
            unsigned long long mk0 = masks[0], mk1 = masks[1];
            if (tid == 0) *nseg_s = __popcll(mk0) + __popcll(mk1);
            if (flag) {
                int rank = (tid < 64)
                    ? __popcll(mk0 & ((1ull << tid) - 1ull))
                    : __popcll(mk0) + ((tid == 64) ? 0 : __popcll(mk1 & ((1ull << (tid - 64)) - 1ull)));
                segstart[rank] = tid;
                segnode[rank] = rs_local[tid];
            }
        }
        __syncthreads();   // B4: segstart/segnode/nseg visible

        // segment reduce: interior = plain store, boundary = atomic
        {
            const int colc = tid & 127;
            const int sg = tid >> 7;               // 4 streams
            const int ns = *nseg_s;
            for (int s2 = sg; s2 < ns; s2 += 4) {
                int a = segstart[s2];
                int bnd = (s2 + 1 < ns) ? segstart[s2 + 1] : 128;
                float sum = 0.f;
                for (int rr = a; rr < bnd; ++rr) sum += bflo((uint32_t)Vl[rr * 128 + colc]);
                int node = segnode[s2];
                bool interior = (s2 > 0) && (s2 + 1 < ns);
                if (interior) out[(size_t)node * 128 + colc] = sum;
                else          atomicAdd(&out[(size_t)node * 128 + colc], sum);
                if (colc == 0) {
                    float ds = 0.f;
                    for (int rr = a; rr < bnd; ++rr) ds += pl[rr];
                    if (interior) denom[node] = ds;
                    else          atomicAdd(&denom[node], ds);
                }
            }
        }
        __syncthreads();   // B5: reduce done; A region reusable

#pragma unroll
        for (int i = 0; i < 4; ++i) curA[i] = nxtA[i];
    }
}

// ---------------- normalize: out /= denom[node] ---------------------------
__global__ void normalize_kernel(float* __restrict__ out, const float* __restrict__ denom) {
    int i = blockIdx.x * blockDim.x + threadIdx.x;   // one float4 each
    if (i >= NN * 128 / 4) return;
    int node = (i * 4) >> 7;
    float d = denom[node];
    float inv = d > 0.f ? 1.0f / d : 0.f;
    float4* o = reinterpret_cast<float4*>(out) + i;
    float4 v = *o;
    v.x *= inv; v.y *= inv; v.z *= inv; v.w *= inv;
    *o = v;
}

extern "C" void kernel_launch(void* const* d_in, const int* in_sizes, int n_in,
                              void* d_out, int out_size, void* d_ws, size_t ws_size,
                              hipStream_t stream) {
    const float* nodes = (const float*)d_in[0];
    const float* edges = (const float*)d_in[1];
    const int*   eidx  = (const int*)d_in[2];     // row0 = sender, row1 = receiver
    const float* Wq = (const float*)d_in[3];
    const float* bq = (const float*)d_in[4];
    const float* Wk = (const float*)d_in[5];
    const float* bk = (const float*)d_in[6];
    const float* Wv = (const float*)d_in[7];
    const float* bv = (const float*)d_in[8];
    const int* sidx = eidx;
    const int* ridx = eidx + NE;

    // workspace layout (16B aligned):
    char* ws = (char*)d_ws;
    unsigned short* wq_bf = (unsigned short*)ws;          // Wq||Wk stacked, then Wv
    unsigned short* wv_bf = wq_bf + 65536;
    unsigned short* q_bf  = (unsigned short*)(ws + 163840);
    unsigned short* k_bf  = q_bf + (size_t)NN * 128;
    char* ws2 = ws + 163840 + 2 * (size_t)NN * 128 * 2;   // after q,k (25.6 MB)
    int*   cnt   = (int*)ws2;                             // NN
    int*   offs  = cnt + NN;                              // NN (cursor)
    int*   offs2 = offs + NN;                             // NN+1 (pristine CSR)
    int*   ssort = offs2 + NN + 4;                        // NE
    int*   rsort = ssort + NE;                            // NE
    unsigned short* esort = (unsigned short*)(rsort + NE);// NE*128 bf16 (410 MB)
    float* denom = (float*)(esort + (size_t)NE * 128);    // NN
    float* out = (float*)d_out;

    init_zero<<<2048, 256, 0, stream>>>((float4*)out, denom, cnt);
    cast_w_kernel<<<320, 256, 0, stream>>>(Wq, Wk, Wv, wq_bf);
    hist_kernel<<<(NE + 255) / 256, 256, 0, stream>>>(ridx, cnt);
    scan_kernel<<<1, 1024, 0, stream>>>(cnt, offs, offs2);
    proj_qk<<<(NN + 63) / 64, 256, 0, stream>>>(nodes, wq_bf, bq, bk, q_bf, k_bf, NN);
    edge_sort<<<NE / 128, 512, 0, stream>>>(edges, ridx, sidx, offs, esort, ssort, rsort);
    fused_sorted<<<500, 512, 0, stream>>>(esort, wv_bf, bv, q_bf, k_bf, ssort, rsort,
                                          out, denom, 25);
    normalize_kernel<<<(NN * 128 / 4 + 255) / 256, 256, 0, stream>>>(out, denom);
}

// Round 9
// 884.997 us; speedup vs baseline: 1.2615x; 1.2615x over previous
//
#include <hip/hip_runtime.h>
#include <hip/hip_bf16.h>
#include <cstdint>

#define NN 50000
#define NE 1600000
#define DV 256
#define DA 128

using floatx4 = __attribute__((ext_vector_type(4))) float;
using shortx8 = __attribute__((ext_vector_type(8))) short;

__device__ __forceinline__ unsigned short f2bf(float f) {
    union { float f; uint32_t u; } v; v.f = f;
    uint32_t u = v.u;
    uint32_t r = (u + 0x7FFFu + ((u >> 16) & 1u)) >> 16;   // RNE
    return (unsigned short)r;
}
__device__ __forceinline__ float bflo(uint32_t u) {
    union { uint32_t u; float f; } v; v.u = u << 16; return v.f;
}
__device__ __forceinline__ float bfhi(uint32_t u) {
    union { uint32_t u; float f; } v; v.u = u & 0xFFFF0000u; return v.f;
}
__device__ __forceinline__ shortx8 pack8(float4 a, float4 b) {
    shortx8 u;
    u[0] = (short)f2bf(a.x); u[1] = (short)f2bf(a.y);
    u[2] = (short)f2bf(a.z); u[3] = (short)f2bf(a.w);
    u[4] = (short)f2bf(b.x); u[5] = (short)f2bf(b.y);
    u[6] = (short)f2bf(b.z); u[7] = (short)f2bf(b.w);
    return u;
}

// ---------------- zero out + denom + cnt ----------------------------------
__global__ void init_zero(float4* __restrict__ out, float* __restrict__ denom,
                          int* __restrict__ cnt) {
    const float4 z = make_float4(0.f, 0.f, 0.f, 0.f);
    int i = blockIdx.x * blockDim.x + threadIdx.x;
    const int stride = gridDim.x * blockDim.x;
    for (int j = i; j < NN * 128 / 4; j += stride) out[j] = z;
    if (i < NN) { denom[i] = 0.f; cnt[i] = 0; }
}

// ---------------- cast weights fp32 -> bf16 -------------------------------
__global__ void cast_w_kernel(const float* __restrict__ wq, const float* __restrict__ wk,
                              const float* __restrict__ wv, unsigned short* __restrict__ out) {
    int i = blockIdx.x * blockDim.x + threadIdx.x;
    if (i < 32768)       out[i] = f2bf(wq[i]);
    else if (i < 65536)  out[i] = f2bf(wk[i - 32768]);
    else if (i < 81920)  out[i] = f2bf(wv[i - 65536]);
}

// ---------------- CSR build -----------------------------------------------
__global__ void hist_kernel(const int* __restrict__ ridx, int* __restrict__ cnt) {
    int e = blockIdx.x * blockDim.x + threadIdx.x;
    if (e < NE) atomicAdd(&cnt[ridx[e]], 1);
}

__global__ __launch_bounds__(1024)
void scan_kernel(const int* __restrict__ cnt, int* __restrict__ offs, int* __restrict__ offs2) {
    __shared__ int part[1024];
    const int tid = threadIdx.x;
    const int PER = (NN + 1023) / 1024;   // 49
    int base = tid * PER;
    int s = 0;
    for (int i = 0; i < PER; ++i) { int idx = base + i; if (idx < NN) s += cnt[idx]; }
    part[tid] = s;
    __syncthreads();
    for (int off = 1; off < 1024; off <<= 1) {
        int v = (tid >= off) ? part[tid - off] : 0;
        __syncthreads();
        part[tid] += v;
        __syncthreads();
    }
    int excl = (tid == 0) ? 0 : part[tid - 1];
    for (int i = 0; i < PER; ++i) {
        int idx = base + i;
        if (idx < NN) { offs[idx] = excl; offs2[idx] = excl; excl += cnt[idx]; }
    }
    if (tid == 0) offs2[NN] = NE;
}

// ---------------- fused Q,K projection: [NN,256] x [256,256]^T ------------
__global__ __launch_bounds__(256)
void proj_qk(const float* __restrict__ A, const unsigned short* __restrict__ Wst,
             const float* __restrict__ bq, const float* __restrict__ bk,
             unsigned short* __restrict__ qbf, unsigned short* __restrict__ kbf, int M) {
    __shared__ unsigned short Al[64 * 32];
    __shared__ unsigned short Bl[256 * 32];
    const int tid = threadIdx.x;
    const int lane = tid & 63, w = tid >> 6;
    const int m0 = blockIdx.x * 64;
    constexpr int K = 256;

    floatx4 acc[16];
#pragma unroll
    for (int i = 0; i < 16; ++i) acc[i] = (floatx4)0.0f;

    for (int kk = 0; kk < K; kk += 32) {
#pragma unroll
        for (int it = 0; it < 2; ++it) {
            int j = tid + it * 256;
            int row = j >> 3;
            int c4 = (j & 7) * 4;
            float4 f = make_float4(0.f, 0.f, 0.f, 0.f);
            int gm = m0 + row;
            if (gm < M) f = *reinterpret_cast<const float4*>(A + (size_t)gm * K + kk + c4);
            ushort4 u; u.x = f2bf(f.x); u.y = f2bf(f.y); u.z = f2bf(f.z); u.w = f2bf(f.w);
            *reinterpret_cast<ushort4*>(&Al[row * 32 + c4]) = u;
        }
#pragma unroll
        for (int it = 0; it < 4; ++it) {
            int j = tid + it * 256;
            int row = j >> 2;
            int c8 = (j & 3) * 8;
            uint4 v = *reinterpret_cast<const uint4*>(Wst + (size_t)row * K + kk + c8);
            *reinterpret_cast<uint4*>(&Bl[row * 32 + c8]) = v;
        }
        __syncthreads();
        shortx8 af = *reinterpret_cast<const shortx8*>(&Al[(w * 16 + (lane & 15)) * 32 + 8 * (lane >> 4)]);
#pragma unroll
        for (int nt = 0; nt < 16; ++nt) {
            shortx8 bf = *reinterpret_cast<const shortx8*>(&Bl[(nt * 16 + (lane & 15)) * 32 + 8 * (lane >> 4)]);
            acc[nt] = __builtin_amdgcn_mfma_f32_16x16x32_bf16(af, bf, acc[nt], 0, 0, 0);
        }
        __syncthreads();
    }
    const int col = lane & 15;
    const int rbase = m0 + w * 16 + 4 * (lane >> 4);
#pragma unroll
    for (int nt = 0; nt < 16; ++nt) {
        int gn = nt * 16 + col;
        bool isq = gn < 128;
        int oc = isq ? gn : gn - 128;
        float b = isq ? bq[oc] : bk[oc];
        unsigned short* O = isq ? qbf : kbf;
#pragma unroll
        for (int reg = 0; reg < 4; ++reg) {
            int gm = rbase + reg;
            if (gm < M) {
                float v = acc[nt][reg] + b;
                v = v > 0.f ? v : 0.01f * v;
                O[(size_t)gm * 128 + oc] = f2bf(v);
            }
        }
    }
}

// ---- pure permute: edges (fp32, natural) -> esort (bf16, receiver-sorted) -
__global__ __launch_bounds__(512)
void edge_sort(const float* __restrict__ Ed, const int* __restrict__ ridx,
               const int* __restrict__ sidx, int* __restrict__ cursor,
               unsigned short* __restrict__ esort, int* __restrict__ ssort,
               int* __restrict__ rsort) {
    const int tid = threadIdx.x;
    const int lane = tid & 63;
    const size_t m0 = (size_t)blockIdx.x * 128;    // NE % 128 == 0
    const int erow = tid >> 2, qt = tid & 3;
    const size_t e = m0 + erow;

    const float* arow = Ed + e * 128 + qt * 32;    // this thread's 128B quarter
    float4 f[8];
#pragma unroll
    for (int i = 0; i < 8; ++i) f[i] = *reinterpret_cast<const float4*>(arow + i * 4);

    int pos = 0;
    if (qt == 0) {
        int r = ridx[e];
        pos = atomicAdd(&cursor[r], 1);
        ssort[pos] = sidx[e];
        rsort[pos] = r;
    }
    pos = __shfl(pos, lane & ~3);                  // broadcast within edge quad

    unsigned short* dst = esort + (size_t)pos * 128 + qt * 32;
#pragma unroll
    for (int i = 0; i < 4; ++i) {
        shortx8 u = pack8(f[2 * i], f[2 * i + 1]);
        *reinterpret_cast<shortx8*>(dst + i * 8) = u;
    }
}

// ---- fused consumer: seq bf16 sorted-edge reads, logits, V-GEMM, reduce ---
// 12500 blocks x 512 threads (8 waves), ONE 128-edge tile per block.
// A in REGISTERS (strided 16B reads = direct MFMA fragments, no A-LDS).
// LDS ~35KB: [0,32768) Wv frags, aliased as Vl bf16[128][128] post-MFMA;
// [32768,33280) pl; [33280,33792) rs_local; [33792,34304) segstart;
// [34304,34816) segnode; [34816,34832) masks; [34832,34836) nseg.
__global__ __launch_bounds__(512)
void fused2(const unsigned short* __restrict__ esort, const unsigned short* __restrict__ wv_bf,
            const float* __restrict__ bv,
            const unsigned short* __restrict__ qbf, const unsigned short* __restrict__ kbf,
            const int* __restrict__ ssort, const int* __restrict__ rsort,
            float* __restrict__ out, float* __restrict__ denom) {
    __shared__ __align__(16) char smem[34848];
    unsigned short* Vl = reinterpret_cast<unsigned short*>(smem);   // alias of Wv, post-MFMA
    float* pl       = reinterpret_cast<float*>(smem + 32768);
    int*   rs_local = reinterpret_cast<int*>(smem + 33280);
    int*   segstart = reinterpret_cast<int*>(smem + 33792);
    int*   segnode  = reinterpret_cast<int*>(smem + 34304);
    unsigned long long* masks = reinterpret_cast<unsigned long long*>(smem + 34816);
    int* nseg_s = reinterpret_cast<int*>(smem + 34832);

    const int tid = threadIdx.x;
    const int lane = tid & 63, w = tid >> 6;
    const size_t m0 = (size_t)blockIdx.x * 128;    // NE % 128 == 0

    // ---- A fragments straight to registers ----
    // lane l holds A[row=w*16+(l&15)][k=kt*32+(l>>4)*8 .. +8] for kt=0..3
    const unsigned short* arow =
        esort + (m0 + w * 16 + (lane & 15)) * 128 + (lane >> 4) * 8;
    shortx8 afr[4];
#pragma unroll
    for (int kt = 0; kt < 4; ++kt)
        afr[kt] = *reinterpret_cast<const shortx8*>(arow + kt * 32);

    // ---- Wv -> LDS fragment-linear ----
#pragma unroll
    for (int it = 0; it < 4; ++it) {
        int s = tid + it * 512;
        int g = s >> 6, l = s & 63;
        int kt4 = g >> 3, nt = g & 7;
        uint4 v = *reinterpret_cast<const uint4*>(
            wv_bf + (size_t)(nt * 16 + (l & 15)) * 128 + kt4 * 32 + 8 * (l >> 4));
        *reinterpret_cast<uint4*>(smem + s * 16) = v;
    }

    // ---- logits: 4 lanes per edge, 32 dims each ----
    const int erow = tid >> 2, qt = tid & 3;
    {
        const int sN = ssort[m0 + erow];
        const int rN = rsort[m0 + erow];
        if (qt == 0) rs_local[erow] = rN;
        const uint4* kp = reinterpret_cast<const uint4*>(kbf + (size_t)sN * 128 + qt * 32);
        const uint4* qp = reinterpret_cast<const uint4*>(qbf + (size_t)rN * 128 + qt * 32);
        float acq = 0.f;
#pragma unroll
        for (int i = 0; i < 4; ++i) {
            uint4 qa = qp[i], ka = kp[i];
            acq += bflo(qa.x) * bflo(ka.x) + bfhi(qa.x) * bfhi(ka.x);
            acq += bflo(qa.y) * bflo(ka.y) + bfhi(qa.y) * bfhi(ka.y);
            acq += bflo(qa.z) * bflo(ka.z) + bfhi(qa.z) * bfhi(ka.z);
            acq += bflo(qa.w) * bflo(ka.w) + bfhi(qa.w) * bfhi(ka.w);
        }
        acq += __shfl_xor(acq, 1);
        acq += __shfl_xor(acq, 2);
        if (qt == 0) pl[erow] = __expf(acq * 0.08838834764831845f);
    }
    __syncthreads();   // B1: Wv staged, pl/rs_local visible

    // mask step 1 (waves 0,1)
    if (tid < 128) {
        bool flag = (tid == 0) || (rs_local[tid] != rs_local[tid - 1]);
        unsigned long long mk = __ballot(flag);
        if (lane == 0) masks[w] = mk;
    }

    // ---- MFMA: A regs x Wv LDS ----
    floatx4 acc[8];
#pragma unroll
    for (int i = 0; i < 8; ++i) acc[i] = (floatx4)0.0f;
#pragma unroll
    for (int kt = 0; kt < 4; ++kt) {
#pragma unroll
        for (int nt = 0; nt < 8; ++nt) {
            shortx8 bfr = *reinterpret_cast<const shortx8*>(smem + (((kt * 8 + nt) * 64 + lane) << 4));
            acc[nt] = __builtin_amdgcn_mfma_f32_16x16x32_bf16(afr[kt], bfr, acc[nt], 0, 0, 0);
        }
    }
    __syncthreads();   // B2: MFMA done (Wv region free), masks visible

    // mask step 2
    if (tid < 128) {
        bool flag = (tid == 0) || (rs_local[tid] != rs_local[tid - 1]);
        unsigned long long mk0 = masks[0], mk1 = masks[1];
        if (tid == 0) *nseg_s = __popcll(mk0) + __popcll(mk1);
        if (flag) {
            int rank = (tid < 64)
                ? __popcll(mk0 & ((1ull << tid) - 1ull))
                : __popcll(mk0) + ((tid == 64) ? 0 : __popcll(mk1 & ((1ull << (tid - 64)) - 1ull)));
            segstart[rank] = tid;
            segnode[rank] = rs_local[tid];
        }
    }

    // epilogue: bias + lrelu, scale by p -> Vl (aliases Wv region)
    // C layout: edge m = w*16 + (lane>>4)*4 + reg, col = nt*16 + (lane&15)
    const int colb = lane & 15;
    const int mrow = w * 16 + (lane >> 4) * 4;
    float pe[4];
#pragma unroll
    for (int reg = 0; reg < 4; ++reg) pe[reg] = pl[mrow + reg];
#pragma unroll
    for (int nt = 0; nt < 8; ++nt) {
        float b = bv[nt * 16 + colb];
#pragma unroll
        for (int reg = 0; reg < 4; ++reg) {
            float v = acc[nt][reg] + b;
            v = v > 0.f ? v : 0.01f * v;
            Vl[(mrow + reg) * 128 + nt * 16 + colb] = f2bf(v * pe[reg]);
        }
    }
    __syncthreads();   // B3: Vl + segstart/segnode/nseg visible

    // ---- segment reduce: interior plain store, boundary atomic ----
    const int colc = tid & 127;
    const int sg = tid >> 7;                 // 4 segment streams
    const int ns = *nseg_s;
    for (int s2 = sg; s2 < ns; s2 += 4) {
        int a = segstart[s2];
        int bnd = (s2 + 1 < ns) ? segstart[s2 + 1] : 128;
        float sum = 0.f;
        for (int rr = a; rr < bnd; ++rr) sum += bflo((uint32_t)Vl[rr * 128 + colc]);
        int node = segnode[s2];
        bool interior = (s2 > 0) && (s2 + 1 < ns);
        if (interior) out[(size_t)node * 128 + colc] = sum;
        else          atomicAdd(&out[(size_t)node * 128 + colc], sum);
        if (colc == 0) {
            float ds = 0.f;
            for (int rr = a; rr < bnd; ++rr) ds += pl[rr];
            if (interior) denom[node] = ds;
            else          atomicAdd(&denom[node], ds);
        }
    }
}

// ---------------- normalize: out /= denom[node] ---------------------------
__global__ void normalize_kernel(float* __restrict__ out, const float* __restrict__ denom) {
    int i = blockIdx.x * blockDim.x + threadIdx.x;   // one float4 each
    if (i >= NN * 128 / 4) return;
    int node = (i * 4) >> 7;
    float d = denom[node];
    float inv = d > 0.f ? 1.0f / d : 0.f;
    float4* o = reinterpret_cast<float4*>(out) + i;
    float4 v = *o;
    v.x *= inv; v.y *= inv; v.z *= inv; v.w *= inv;
    *o = v;
}

extern "C" void kernel_launch(void* const* d_in, const int* in_sizes, int n_in,
                              void* d_out, int out_size, void* d_ws, size_t ws_size,
                              hipStream_t stream) {
    const float* nodes = (const float*)d_in[0];
    const float* edges = (const float*)d_in[1];
    const int*   eidx  = (const int*)d_in[2];     // row0 = sender, row1 = receiver
    const float* Wq = (const float*)d_in[3];
    const float* bq = (const float*)d_in[4];
    const float* Wk = (const float*)d_in[5];
    const float* bk = (const float*)d_in[6];
    const float* Wv = (const float*)d_in[7];
    const float* bv = (const float*)d_in[8];
    const int* sidx = eidx;
    const int* ridx = eidx + NE;

    // workspace layout (16B aligned):
    char* ws = (char*)d_ws;
    unsigned short* wq_bf = (unsigned short*)ws;          // Wq||Wk stacked, then Wv
    unsigned short* wv_bf = wq_bf + 65536;
    unsigned short* q_bf  = (unsigned short*)(ws + 163840);
    unsigned short* k_bf  = q_bf + (size_t)NN * 128;
    char* ws2 = ws + 163840 + 2 * (size_t)NN * 128 * 2;   // after q,k (25.6 MB)
    int*   cnt   = (int*)ws2;                             // NN
    int*   offs  = cnt + NN;                              // NN (cursor)
    int*   offs2 = offs + NN;                             // NN+1 (pristine CSR)
    int*   ssort = offs2 + NN + 4;                        // NE
    int*   rsort = ssort + NE;                            // NE
    unsigned short* esort = (unsigned short*)(rsort + NE);// NE*128 bf16 (410 MB)
    float* denom = (float*)(esort + (size_t)NE * 128);    // NN
    float* out = (float*)d_out;

    init_zero<<<2048, 256, 0, stream>>>((float4*)out, denom, cnt);
    cast_w_kernel<<<320, 256, 0, stream>>>(Wq, Wk, Wv, wq_bf);
    hist_kernel<<<(NE + 255) / 256, 256, 0, stream>>>(ridx, cnt);
    scan_kernel<<<1, 1024, 0, stream>>>(cnt, offs, offs2);
    proj_qk<<<(NN + 63) / 64, 256, 0, stream>>>(nodes, wq_bf, bq, bk, q_bf, k_bf, NN);
    edge_sort<<<NE / 128, 512, 0, stream>>>(edges, ridx, sidx, offs, esort, ssort, rsort);
    fused2<<<NE / 128, 512, 0, stream>>>(esort, wv_bf, bv, q_bf, k_bf, ssort, rsort,
                                         out, denom);
    normalize_kernel<<<(NN * 128 / 4 + 255) / 256, 256, 0, stream>>>(out, denom);
}

// Round 10
// 836.210 us; speedup vs baseline: 1.3351x; 1.0583x over previous
//
#include <hip/hip_runtime.h>
#include <hip/hip_bf16.h>
#include <cstdint>

#define NN 50000
#define NE 1600000
#define DV 256
#define DA 128

using floatx4 = __attribute__((ext_vector_type(4))) float;
using shortx8 = __attribute__((ext_vector_type(8))) short;

__device__ __forceinline__ unsigned short f2bf(float f) {
    union { float f; uint32_t u; } v; v.f = f;
    uint32_t u = v.u;
    uint32_t r = (u + 0x7FFFu + ((u >> 16) & 1u)) >> 16;   // RNE
    return (unsigned short)r;
}
__device__ __forceinline__ float bflo(uint32_t u) {
    union { uint32_t u; float f; } v; v.u = u << 16; return v.f;
}
__device__ __forceinline__ float bfhi(uint32_t u) {
    union { uint32_t u; float f; } v; v.u = u & 0xFFFF0000u; return v.f;
}
__device__ __forceinline__ shortx8 pack8(float4 a, float4 b) {
    shortx8 u;
    u[0] = (short)f2bf(a.x); u[1] = (short)f2bf(a.y);
    u[2] = (short)f2bf(a.z); u[3] = (short)f2bf(a.w);
    u[4] = (short)f2bf(b.x); u[5] = (short)f2bf(b.y);
    u[6] = (short)f2bf(b.z); u[7] = (short)f2bf(b.w);
    return u;
}

// ---------------- zero out + denom + cnt ----------------------------------
__global__ void init_zero(float4* __restrict__ out, float* __restrict__ denom,
                          int* __restrict__ cnt) {
    const float4 z = make_float4(0.f, 0.f, 0.f, 0.f);
    int i = blockIdx.x * blockDim.x + threadIdx.x;
    const int stride = gridDim.x * blockDim.x;
    for (int j = i; j < NN * 128 / 4; j += stride) out[j] = z;
    if (i < NN) { denom[i] = 0.f; cnt[i] = 0; }
}

// ---------------- cast weights fp32 -> bf16 -------------------------------
__global__ void cast_w_kernel(const float* __restrict__ wq, const float* __restrict__ wk,
                              const float* __restrict__ wv, unsigned short* __restrict__ out) {
    int i = blockIdx.x * blockDim.x + threadIdx.x;
    if (i < 32768)       out[i] = f2bf(wq[i]);
    else if (i < 65536)  out[i] = f2bf(wk[i - 32768]);
    else if (i < 81920)  out[i] = f2bf(wv[i - 65536]);
}

// ---------------- CSR build -----------------------------------------------
__global__ void hist_kernel(const int* __restrict__ ridx, int* __restrict__ cnt) {
    int e = blockIdx.x * blockDim.x + threadIdx.x;
    if (e < NE) atomicAdd(&cnt[ridx[e]], 1);
}

__global__ __launch_bounds__(1024)
void scan_kernel(const int* __restrict__ cnt, int* __restrict__ offs, int* __restrict__ offs2) {
    __shared__ int part[1024];
    const int tid = threadIdx.x;
    const int PER = (NN + 1023) / 1024;   // 49
    int base = tid * PER;
    int s = 0;
    for (int i = 0; i < PER; ++i) { int idx = base + i; if (idx < NN) s += cnt[idx]; }
    part[tid] = s;
    __syncthreads();
    for (int off = 1; off < 1024; off <<= 1) {
        int v = (tid >= off) ? part[tid - off] : 0;
        __syncthreads();
        part[tid] += v;
        __syncthreads();
    }
    int excl = (tid == 0) ? 0 : part[tid - 1];
    for (int i = 0; i < PER; ++i) {
        int idx = base + i;
        if (idx < NN) { offs[idx] = excl; offs2[idx] = excl; excl += cnt[idx]; }
    }
    if (tid == 0) offs2[NN] = NE;
}

// ---------------- fused Q,K projection: [NN,256] x [256,256]^T ------------
__global__ __launch_bounds__(256)
void proj_qk(const float* __restrict__ A, const unsigned short* __restrict__ Wst,
             const float* __restrict__ bq, const float* __restrict__ bk,
             unsigned short* __restrict__ qbf, unsigned short* __restrict__ kbf, int M) {
    __shared__ unsigned short Al[64 * 32];
    __shared__ unsigned short Bl[256 * 32];
    const int tid = threadIdx.x;
    const int lane = tid & 63, w = tid >> 6;
    const int m0 = blockIdx.x * 64;
    constexpr int K = 256;

    floatx4 acc[16];
#pragma unroll
    for (int i = 0; i < 16; ++i) acc[i] = (floatx4)0.0f;

    for (int kk = 0; kk < K; kk += 32) {
#pragma unroll
        for (int it = 0; it < 2; ++it) {
            int j = tid + it * 256;
            int row = j >> 3;
            int c4 = (j & 7) * 4;
            float4 f = make_float4(0.f, 0.f, 0.f, 0.f);
            int gm = m0 + row;
            if (gm < M) f = *reinterpret_cast<const float4*>(A + (size_t)gm * K + kk + c4);
            ushort4 u; u.x = f2bf(f.x); u.y = f2bf(f.y); u.z = f2bf(f.z); u.w = f2bf(f.w);
            *reinterpret_cast<ushort4*>(&Al[row * 32 + c4]) = u;
        }
#pragma unroll
        for (int it = 0; it < 4; ++it) {
            int j = tid + it * 256;
            int row = j >> 2;
            int c8 = (j & 3) * 8;
            uint4 v = *reinterpret_cast<const uint4*>(Wst + (size_t)row * K + kk + c8);
            *reinterpret_cast<uint4*>(&Bl[row * 32 + c8]) = v;
        }
        __syncthreads();
        shortx8 af = *reinterpret_cast<const shortx8*>(&Al[(w * 16 + (lane & 15)) * 32 + 8 * (lane >> 4)]);
#pragma unroll
        for (int nt = 0; nt < 16; ++nt) {
            shortx8 bf = *reinterpret_cast<const shortx8*>(&Bl[(nt * 16 + (lane & 15)) * 32 + 8 * (lane >> 4)]);
            acc[nt] = __builtin_amdgcn_mfma_f32_16x16x32_bf16(af, bf, acc[nt], 0, 0, 0);
        }
        __syncthreads();
    }
    const int col = lane & 15;
    const int rbase = m0 + w * 16 + 4 * (lane >> 4);
#pragma unroll
    for (int nt = 0; nt < 16; ++nt) {
        int gn = nt * 16 + col;
        bool isq = gn < 128;
        int oc = isq ? gn : gn - 128;
        float b = isq ? bq[oc] : bk[oc];
        unsigned short* O = isq ? qbf : kbf;
#pragma unroll
        for (int reg = 0; reg < 4; ++reg) {
            int gm = rbase + reg;
            if (gm < M) {
                float v = acc[nt][reg] + b;
                v = v > 0.f ? v : 0.01f * v;
                O[(size_t)gm * 128 + oc] = f2bf(v);
            }
        }
    }
}

// ---- pure permute: edges (fp32, natural) -> esort (bf16, receiver-sorted) -
// COALESCING FIX vs r9: a 16-lane group owns one edge row; lane c reads fp32
// bytes [c*32,c*32+32) (row-sequential) and writes bf16 bytes [c*16,c*16+16)
// of the destination row -> one contiguous 256B burst per row per store.
__global__ __launch_bounds__(256)
void edge_sort(const float* __restrict__ Ed, const int* __restrict__ ridx,
               const int* __restrict__ sidx, int* __restrict__ cursor,
               unsigned short* __restrict__ esort, int* __restrict__ ssort,
               int* __restrict__ rsort) {
    const int tid = threadIdx.x;
    const int grp = tid >> 4;            // 16 groups per block
    const int c = tid & 15;              // 16B-chunk lane within group
    const int srcLane = tid & 48;        // group-leader lane within wave
    const size_t m0 = (size_t)blockIdx.x * 128;

#pragma unroll
    for (int b = 0; b < 2; ++b) {
        float4 fa[4], fb[4];
        int pos[4];
        // issue all 4 row reads first (independent of atomics)
#pragma unroll
        for (int j = 0; j < 4; ++j) {
            size_t e = m0 + (size_t)(b * 4 + j) * 16 + grp;
            const float* src = Ed + e * 128 + c * 8;
            fa[j] = *reinterpret_cast<const float4*>(src);
            fb[j] = *reinterpret_cast<const float4*>(src + 4);
        }
        // claim sorted slots (leader lane), broadcast
#pragma unroll
        for (int j = 0; j < 4; ++j) {
            size_t e = m0 + (size_t)(b * 4 + j) * 16 + grp;
            int p = 0;
            if (c == 0) {
                int r = ridx[e];
                p = atomicAdd(&cursor[r], 1);
                ssort[p] = sidx[e];
                rsort[p] = r;
            }
            pos[j] = __shfl(p, srcLane);
        }
        // 256B-burst scattered writes
#pragma unroll
        for (int j = 0; j < 4; ++j) {
            shortx8 u = pack8(fa[j], fb[j]);
            *reinterpret_cast<shortx8*>(esort + (size_t)pos[j] * 128 + c * 8) = u;
        }
    }
}

// ---- fused consumer: seq bf16 sorted-edge reads, logits, V-GEMM, reduce ---
// (unchanged from r9)
__global__ __launch_bounds__(512)
void fused2(const unsigned short* __restrict__ esort, const unsigned short* __restrict__ wv_bf,
            const float* __restrict__ bv,
            const unsigned short* __restrict__ qbf, const unsigned short* __restrict__ kbf,
            const int* __restrict__ ssort, const int* __restrict__ rsort,
            float* __restrict__ out, float* __restrict__ denom) {
    __shared__ __align__(16) char smem[34848];
    unsigned short* Vl = reinterpret_cast<unsigned short*>(smem);   // alias of Wv, post-MFMA
    float* pl       = reinterpret_cast<float*>(smem + 32768);
    int*   rs_local = reinterpret_cast<int*>(smem + 33280);
    int*   segstart = reinterpret_cast<int*>(smem + 33792);
    int*   segnode  = reinterpret_cast<int*>(smem + 34304);
    unsigned long long* masks = reinterpret_cast<unsigned long long*>(smem + 34816);
    int* nseg_s = reinterpret_cast<int*>(smem + 34832);

    const int tid = threadIdx.x;
    const int lane = tid & 63, w = tid >> 6;
    const size_t m0 = (size_t)blockIdx.x * 128;    // NE % 128 == 0

    // ---- A fragments straight to registers ----
    const unsigned short* arow =
        esort + (m0 + w * 16 + (lane & 15)) * 128 + (lane >> 4) * 8;
    shortx8 afr[4];
#pragma unroll
    for (int kt = 0; kt < 4; ++kt)
        afr[kt] = *reinterpret_cast<const shortx8*>(arow + kt * 32);

    // ---- Wv -> LDS fragment-linear ----
#pragma unroll
    for (int it = 0; it < 4; ++it) {
        int s = tid + it * 512;
        int g = s >> 6, l = s & 63;
        int kt4 = g >> 3, nt = g & 7;
        uint4 v = *reinterpret_cast<const uint4*>(
            wv_bf + (size_t)(nt * 16 + (l & 15)) * 128 + kt4 * 32 + 8 * (l >> 4));
        *reinterpret_cast<uint4*>(smem + s * 16) = v;
    }

    // ---- logits: 4 lanes per edge, 32 dims each ----
    const int erow = tid >> 2, qt = tid & 3;
    {
        const int sN = ssort[m0 + erow];
        const int rN = rsort[m0 + erow];
        if (qt == 0) rs_local[erow] = rN;
        const uint4* kp = reinterpret_cast<const uint4*>(kbf + (size_t)sN * 128 + qt * 32);
        const uint4* qp = reinterpret_cast<const uint4*>(qbf + (size_t)rN * 128 + qt * 32);
        float acq = 0.f;
#pragma unroll
        for (int i = 0; i < 4; ++i) {
            uint4 qa = qp[i], ka = kp[i];
            acq += bflo(qa.x) * bflo(ka.x) + bfhi(qa.x) * bfhi(ka.x);
            acq += bflo(qa.y) * bflo(ka.y) + bfhi(qa.y) * bfhi(ka.y);
            acq += bflo(qa.z) * bflo(ka.z) + bfhi(qa.z) * bfhi(ka.z);
            acq += bflo(qa.w) * bflo(ka.w) + bfhi(qa.w) * bfhi(ka.w);
        }
        acq += __shfl_xor(acq, 1);
        acq += __shfl_xor(acq, 2);
        if (qt == 0) pl[erow] = __expf(acq * 0.08838834764831845f);
    }
    __syncthreads();   // B1: Wv staged, pl/rs_local visible

    // mask step 1 (waves 0,1)
    if (tid < 128) {
        bool flag = (tid == 0) || (rs_local[tid] != rs_local[tid - 1]);
        unsigned long long mk = __ballot(flag);
        if (lane == 0) masks[w] = mk;
    }

    // ---- MFMA: A regs x Wv LDS ----
    floatx4 acc[8];
#pragma unroll
    for (int i = 0; i < 8; ++i) acc[i] = (floatx4)0.0f;
#pragma unroll
    for (int kt = 0; kt < 4; ++kt) {
#pragma unroll
        for (int nt = 0; nt < 8; ++nt) {
            shortx8 bfr = *reinterpret_cast<const shortx8*>(smem + (((kt * 8 + nt) * 64 + lane) << 4));
            acc[nt] = __builtin_amdgcn_mfma_f32_16x16x32_bf16(afr[kt], bfr, acc[nt], 0, 0, 0);
        }
    }
    __syncthreads();   // B2: MFMA done (Wv region free), masks visible

    // mask step 2
    if (tid < 128) {
        bool flag = (tid == 0) || (rs_local[tid] != rs_local[tid - 1]);
        unsigned long long mk0 = masks[0], mk1 = masks[1];
        if (tid == 0) *nseg_s = __popcll(mk0) + __popcll(mk1);
        if (flag) {
            int rank = (tid < 64)
                ? __popcll(mk0 & ((1ull << tid) - 1ull))
                : __popcll(mk0) + ((tid == 64) ? 0 : __popcll(mk1 & ((1ull << (tid - 64)) - 1ull)));
            segstart[rank] = tid;
            segnode[rank] = rs_local[tid];
        }
    }

    // epilogue: bias + lrelu, scale by p -> Vl (aliases Wv region)
    const int colb = lane & 15;
    const int mrow = w * 16 + (lane >> 4) * 4;
    float pe[4];
#pragma unroll
    for (int reg = 0; reg < 4; ++reg) pe[reg] = pl[mrow + reg];
#pragma unroll
    for (int nt = 0; nt < 8; ++nt) {
        float b = bv[nt * 16 + colb];
#pragma unroll
        for (int reg = 0; reg < 4; ++reg) {
            float v = acc[nt][reg] + b;
            v = v > 0.f ? v : 0.01f * v;
            Vl[(mrow + reg) * 128 + nt * 16 + colb] = f2bf(v * pe[reg]);
        }
    }
    __syncthreads();   // B3: Vl + segstart/segnode/nseg visible

    // ---- segment reduce: interior plain store, boundary atomic ----
    const int colc = tid & 127;
    const int sg = tid >> 7;                 // 4 segment streams
    const int ns = *nseg_s;
    for (int s2 = sg; s2 < ns; s2 += 4) {
        int a = segstart[s2];
        int bnd = (s2 + 1 < ns) ? segstart[s2 + 1] : 128;
        float sum = 0.f;
        for (int rr = a; rr < bnd; ++rr) sum += bflo((uint32_t)Vl[rr * 128 + colc]);
        int node = segnode[s2];
        bool interior = (s2 > 0) && (s2 + 1 < ns);
        if (interior) out[(size_t)node * 128 + colc] = sum;
        else          atomicAdd(&out[(size_t)node * 128 + colc], sum);
        if (colc == 0) {
            float ds = 0.f;
            for (int rr = a; rr < bnd; ++rr) ds += pl[rr];
            if (interior) denom[node] = ds;
            else          atomicAdd(&denom[node], ds);
        }
    }
}

// ---------------- normalize: out /= denom[node] ---------------------------
__global__ void normalize_kernel(float* __restrict__ out, const float* __restrict__ denom) {
    int i = blockIdx.x * blockDim.x + threadIdx.x;   // one float4 each
    if (i >= NN * 128 / 4) return;
    int node = (i * 4) >> 7;
    float d = denom[node];
    float inv = d > 0.f ? 1.0f / d : 0.f;
    float4* o = reinterpret_cast<float4*>(out) + i;
    float4 v = *o;
    v.x *= inv; v.y *= inv; v.z *= inv; v.w *= inv;
    *o = v;
}

extern "C" void kernel_launch(void* const* d_in, const int* in_sizes, int n_in,
                              void* d_out, int out_size, void* d_ws, size_t ws_size,
                              hipStream_t stream) {
    const float* nodes = (const float*)d_in[0];
    const float* edges = (const float*)d_in[1];
    const int*   eidx  = (const int*)d_in[2];     // row0 = sender, row1 = receiver
    const float* Wq = (const float*)d_in[3];
    const float* bq = (const float*)d_in[4];
    const float* Wk = (const float*)d_in[5];
    const float* bk = (const float*)d_in[6];
    const float* Wv = (const float*)d_in[7];
    const float* bv = (const float*)d_in[8];
    const int* sidx = eidx;
    const int* ridx = eidx + NE;

    // workspace layout (16B aligned):
    char* ws = (char*)d_ws;
    unsigned short* wq_bf = (unsigned short*)ws;          // Wq||Wk stacked, then Wv
    unsigned short* wv_bf = wq_bf + 65536;
    unsigned short* q_bf  = (unsigned short*)(ws + 163840);
    unsigned short* k_bf  = q_bf + (size_t)NN * 128;
    char* ws2 = ws + 163840 + 2 * (size_t)NN * 128 * 2;   // after q,k (25.6 MB)
    int*   cnt   = (int*)ws2;                             // NN
    int*   offs  = cnt + NN;                              // NN (cursor)
    int*   offs2 = offs + NN;                             // NN+1 (pristine CSR)
    int*   ssort = offs2 + NN + 4;                        // NE
    int*   rsort = ssort + NE;                            // NE
    unsigned short* esort = (unsigned short*)(rsort + NE);// NE*128 bf16 (410 MB)
    float* denom = (float*)(esort + (size_t)NE * 128);    // NN
    float* out = (float*)d_out;

    init_zero<<<2048, 256, 0, stream>>>((float4*)out, denom, cnt);
    cast_w_kernel<<<320, 256, 0, stream>>>(Wq, Wk, Wv, wq_bf);
    hist_kernel<<<(NE + 255) / 256, 256, 0, stream>>>(ridx, cnt);
    scan_kernel<<<1, 1024, 0, stream>>>(cnt, offs, offs2);
    proj_qk<<<(NN + 63) / 64, 256, 0, stream>>>(nodes, wq_bf, bq, bk, q_bf, k_bf, NN);
    edge_sort<<<NE / 128, 256, 0, stream>>>(edges, ridx, sidx, offs, esort, ssort, rsort);
    fused2<<<NE / 128, 512, 0, stream>>>(esort, wv_bf, bv, q_bf, k_bf, ssort, rsort,
                                         out, denom);
    normalize_kernel<<<(NN * 128 / 4 + 255) / 256, 256, 0, stream>>>(out, denom);
}

// Round 11
// 816.524 us; speedup vs baseline: 1.3673x; 1.0241x over previous
//
#include <hip/hip_runtime.h>
#include <hip/hip_bf16.h>
#include <cstdint>

#define NN 50000
#define NE 1600000
#define DV 256
#define DA 128
#define CHUNK 320000          // edges per chunk; NE = 5 * CHUNK
#define NCH 5
#define CBLK (CHUNK / 128)    // 2500 blocks per v_chunk launch

using floatx4 = __attribute__((ext_vector_type(4))) float;
using shortx8 = __attribute__((ext_vector_type(8))) short;

__device__ __forceinline__ unsigned short f2bf(float f) {
    union { float f; uint32_t u; } v; v.f = f;
    uint32_t u = v.u;
    uint32_t r = (u + 0x7FFFu + ((u >> 16) & 1u)) >> 16;   // RNE
    return (unsigned short)r;
}
__device__ __forceinline__ float bflo(uint32_t u) {
    union { uint32_t u; float f; } v; v.u = u << 16; return v.f;
}
__device__ __forceinline__ float bfhi(uint32_t u) {
    union { uint32_t u; float f; } v; v.u = u & 0xFFFF0000u; return v.f;
}
__device__ __forceinline__ shortx8 pack8(float4 a, float4 b) {
    shortx8 u;
    u[0] = (short)f2bf(a.x); u[1] = (short)f2bf(a.y);
    u[2] = (short)f2bf(a.z); u[3] = (short)f2bf(a.w);
    u[4] = (short)f2bf(b.x); u[5] = (short)f2bf(b.y);
    u[6] = (short)f2bf(b.z); u[7] = (short)f2bf(b.w);
    return u;
}

// ---------------- zero per-chunk counters ---------------------------------
__global__ void init_cnt(int* __restrict__ cnt) {
    int i = blockIdx.x * blockDim.x + threadIdx.x;
    if (i < NCH * NN) cnt[i] = 0;
}

// ---------------- cast weights fp32 -> bf16 -------------------------------
__global__ void cast_w_kernel(const float* __restrict__ wq, const float* __restrict__ wk,
                              const float* __restrict__ wv, unsigned short* __restrict__ out) {
    int i = blockIdx.x * blockDim.x + threadIdx.x;
    if (i < 32768)       out[i] = f2bf(wq[i]);
    else if (i < 65536)  out[i] = f2bf(wk[i - 32768]);
    else if (i < 81920)  out[i] = f2bf(wv[i - 65536]);
}

// ---------------- per-chunk CSR build --------------------------------------
__global__ void hist5(const int* __restrict__ ridx, int* __restrict__ cnt) {
    int e = blockIdx.x * blockDim.x + threadIdx.x;
    if (e < NE) {
        int c = e / CHUNK;
        atomicAdd(&cnt[c * NN + ridx[e]], 1);
    }
}

// 5 blocks; block b scans chunk b's counts
__global__ __launch_bounds__(1024)
void scan5(const int* __restrict__ cnt, int* __restrict__ offs, int* __restrict__ offs2) {
    __shared__ int part[1024];
    const int b = blockIdx.x;
    const int tid = threadIdx.x;
    const int PER = (NN + 1023) / 1024;   // 49
    const int* cb = cnt + b * NN;
    int base = tid * PER;
    int s = 0;
    for (int i = 0; i < PER; ++i) { int idx = base + i; if (idx < NN) s += cb[idx]; }
    part[tid] = s;
    __syncthreads();
    for (int off = 1; off < 1024; off <<= 1) {
        int v = (tid >= off) ? part[tid - off] : 0;
        __syncthreads();
        part[tid] += v;
        __syncthreads();
    }
    int excl = (tid == 0) ? 0 : part[tid - 1];
    for (int i = 0; i < PER; ++i) {
        int idx = base + i;
        if (idx < NN) {
            offs[b * NN + idx] = excl;
            offs2[b * (NN + 1) + idx] = excl;
            excl += cb[idx];
        }
    }
    if (tid == 0) offs2[b * (NN + 1) + NN] = CHUNK;
}

// scatter local edge ids into per-chunk receiver-sorted order (index-only)
__global__ void scatter5(const int* __restrict__ ridx, int* __restrict__ offs,
                         int* __restrict__ perm) {
    int e = blockIdx.x * blockDim.x + threadIdx.x;
    if (e >= NE) return;
    int c = e / CHUNK;
    int r = ridx[e];
    int pos = atomicAdd(&offs[c * NN + r], 1);
    perm[(size_t)c * CHUNK + pos] = e - c * CHUNK;
}

// ---------------- fused Q,K projection: [NN,256] x [256,256]^T ------------
__global__ __launch_bounds__(256)
void proj_qk(const float* __restrict__ A, const unsigned short* __restrict__ Wst,
             const float* __restrict__ bq, const float* __restrict__ bk,
             unsigned short* __restrict__ qbf, unsigned short* __restrict__ kbf, int M) {
    __shared__ unsigned short Al[64 * 32];
    __shared__ unsigned short Bl[256 * 32];
    const int tid = threadIdx.x;
    const int lane = tid & 63, w = tid >> 6;
    const int m0 = blockIdx.x * 64;
    constexpr int K = 256;

    floatx4 acc[16];
#pragma unroll
    for (int i = 0; i < 16; ++i) acc[i] = (floatx4)0.0f;

    for (int kk = 0; kk < K; kk += 32) {
#pragma unroll
        for (int it = 0; it < 2; ++it) {
            int j = tid + it * 256;
            int row = j >> 3;
            int c4 = (j & 7) * 4;
            float4 f = make_float4(0.f, 0.f, 0.f, 0.f);
            int gm = m0 + row;
            if (gm < M) f = *reinterpret_cast<const float4*>(A + (size_t)gm * K + kk + c4);
            ushort4 u; u.x = f2bf(f.x); u.y = f2bf(f.y); u.z = f2bf(f.z); u.w = f2bf(f.w);
            *reinterpret_cast<ushort4*>(&Al[row * 32 + c4]) = u;
        }
#pragma unroll
        for (int it = 0; it < 4; ++it) {
            int j = tid + it * 256;
            int row = j >> 2;
            int c8 = (j & 3) * 8;
            uint4 v = *reinterpret_cast<const uint4*>(Wst + (size_t)row * K + kk + c8);
            *reinterpret_cast<uint4*>(&Bl[row * 32 + c8]) = v;
        }
        __syncthreads();
        shortx8 af = *reinterpret_cast<const shortx8*>(&Al[(w * 16 + (lane & 15)) * 32 + 8 * (lane >> 4)]);
#pragma unroll
        for (int nt = 0; nt < 16; ++nt) {
            shortx8 bf = *reinterpret_cast<const shortx8*>(&Bl[(nt * 16 + (lane & 15)) * 32 + 8 * (lane >> 4)]);
            acc[nt] = __builtin_amdgcn_mfma_f32_16x16x32_bf16(af, bf, acc[nt], 0, 0, 0);
        }
        __syncthreads();
    }
    const int col = lane & 15;
    const int rbase = m0 + w * 16 + 4 * (lane >> 4);
#pragma unroll
    for (int nt = 0; nt < 16; ++nt) {
        int gn = nt * 16 + col;
        bool isq = gn < 128;
        int oc = isq ? gn : gn - 128;
        float b = isq ? bq[oc] : bk[oc];
        unsigned short* O = isq ? qbf : kbf;
#pragma unroll
        for (int reg = 0; reg < 4; ++reg) {
            int gm = rbase + reg;
            if (gm < M) {
                float v = acc[nt][reg] + b;
                v = v > 0.f ? v : 0.01f * v;
                O[(size_t)gm * 128 + oc] = f2bf(v);
            }
        }
    }
}

// ---- streaming V projection for one chunk -> vbuf (bf16, natural order) ---
// 2500 blocks x 512 threads, 128 edges/block. A packed fp32->bf16 straight
// into MFMA fragment registers (no A-LDS). LDS = 32KB Wv, aliased as Vl.
__global__ __launch_bounds__(512)
void v_chunk(const float* __restrict__ Ed, const unsigned short* __restrict__ wv_bf,
             const float* __restrict__ bv, unsigned short* __restrict__ vout) {
    __shared__ __align__(16) char smem[32768];
    unsigned short* Vl = reinterpret_cast<unsigned short*>(smem);   // alias post-MFMA

    const int tid = threadIdx.x;
    const int lane = tid & 63, w = tid >> 6;
    const size_t m0 = (size_t)blockIdx.x * 128;

    // A fragments: lane holds A[row=w*16+(lane&15)][k=kt*32+(lane>>4)*8 ..+8]
    const float* arow = Ed + (m0 + w * 16 + (lane & 15)) * 128 + (lane >> 4) * 8;
    shortx8 afr[4];
#pragma unroll
    for (int kt = 0; kt < 4; ++kt) {
        float4 fa = *reinterpret_cast<const float4*>(arow + kt * 32);
        float4 fb = *reinterpret_cast<const float4*>(arow + kt * 32 + 4);
        afr[kt] = pack8(fa, fb);
    }

    // Wv -> LDS fragment-linear
#pragma unroll
    for (int it = 0; it < 4; ++it) {
        int s = tid + it * 512;
        int g = s >> 6, l = s & 63;
        int kt4 = g >> 3, nt = g & 7;
        uint4 v = *reinterpret_cast<const uint4*>(
            wv_bf + (size_t)(nt * 16 + (l & 15)) * 128 + kt4 * 32 + 8 * (l >> 4));
        *reinterpret_cast<uint4*>(smem + s * 16) = v;
    }
    __syncthreads();

    floatx4 acc[8];
#pragma unroll
    for (int i = 0; i < 8; ++i) acc[i] = (floatx4)0.0f;
#pragma unroll
    for (int kt = 0; kt < 4; ++kt) {
#pragma unroll
        for (int nt = 0; nt < 8; ++nt) {
            shortx8 bfr = *reinterpret_cast<const shortx8*>(smem + (((kt * 8 + nt) * 64 + lane) << 4));
            acc[nt] = __builtin_amdgcn_mfma_f32_16x16x32_bf16(afr[kt], bfr, acc[nt], 0, 0, 0);
        }
    }
    __syncthreads();     // Wv reads done; alias as Vl

    // bias + lrelu -> bf16 rows in LDS
    const int colb = lane & 15;
    const int mrow = w * 16 + (lane >> 4) * 4;
#pragma unroll
    for (int nt = 0; nt < 8; ++nt) {
        float b = bv[nt * 16 + colb];
#pragma unroll
        for (int reg = 0; reg < 4; ++reg) {
            float v = acc[nt][reg] + b;
            v = v > 0.f ? v : 0.01f * v;
            Vl[(mrow + reg) * 128 + nt * 16 + colb] = f2bf(v);
        }
    }
    __syncthreads();

    // coalesced LDS -> vbuf copy (32KB sequential)
#pragma unroll
    for (int it = 0; it < 4; ++it) {
        int s = tid + it * 512;
        *reinterpret_cast<uint4*>(vout + m0 * 128 + (size_t)s * 8) =
            *reinterpret_cast<const uint4*>(smem + s * 16);
    }
}

// ---- gather for one chunk: per-node wave, V random but L3-HOT -------------
// logits inline (q sequential, k random-L3); out/denom accumulated with
// plain read-modify-write (row owned by exactly one wave per dispatch).
__global__ __launch_bounds__(256)
void gather_chunk(const unsigned short* __restrict__ vbuf, const int* __restrict__ perm_c,
                  const int* __restrict__ sidx_c,
                  const unsigned short* __restrict__ qbf, const unsigned short* __restrict__ kbf,
                  const int* __restrict__ offs2_c, float* __restrict__ out,
                  float* __restrict__ denom, int first) {
    const int lane = threadIdx.x & 63, w = threadIdx.x >> 6;
    const int n = blockIdx.x * 4 + w;            // 12500*4 == NN
    const int g = lane >> 4;                     // edge sub-slot 0..3
    const int c = lane & 15;                     // col group (8 cols)
    const int start = offs2_c[n], end = offs2_c[n + 1];

    // q fragment: 8 dims per lane (replicated across the 4 sub-slots)
    uint4 qv = *reinterpret_cast<const uint4*>(qbf + (size_t)n * 128 + c * 8);

    float acc[8];
#pragma unroll
    for (int i = 0; i < 8; ++i) acc[i] = 0.f;
    float ds = 0.f;

    for (int pos = start + g; pos < end; pos += 4) {
        int e = perm_c[pos];                      // broadcast within 16-lane group
        int s = sidx_c[e];                        // broadcast (L3)
        uint4 kv = *reinterpret_cast<const uint4*>(kbf + (size_t)s * 128 + c * 8);
        float d = bflo(qv.x) * bflo(kv.x) + bfhi(qv.x) * bfhi(kv.x)
                + bflo(qv.y) * bflo(kv.y) + bfhi(qv.y) * bfhi(kv.y)
                + bflo(qv.z) * bflo(kv.z) + bfhi(qv.z) * bfhi(kv.z)
                + bflo(qv.w) * bflo(kv.w) + bfhi(qv.w) * bfhi(kv.w);
        d += __shfl_xor(d, 1);
        d += __shfl_xor(d, 2);
        d += __shfl_xor(d, 4);
        d += __shfl_xor(d, 8);
        float p = __expf(d * 0.08838834764831845f);
        uint4 vv = *reinterpret_cast<const uint4*>(vbuf + (size_t)e * 128 + c * 8);
        acc[0] += p * bflo(vv.x); acc[1] += p * bfhi(vv.x);
        acc[2] += p * bflo(vv.y); acc[3] += p * bfhi(vv.y);
        acc[4] += p * bflo(vv.z); acc[5] += p * bfhi(vv.z);
        acc[6] += p * bflo(vv.w); acc[7] += p * bfhi(vv.w);
        ds += p;
    }
    // reduce across the 4 edge sub-slots
#pragma unroll
    for (int i = 0; i < 8; ++i) {
        acc[i] += __shfl_xor(acc[i], 32);
        acc[i] += __shfl_xor(acc[i], 16);
    }
    ds += __shfl_xor(ds, 32);
    ds += __shfl_xor(ds, 16);

    if (g == 0) {
        float* dst = out + (size_t)n * 128 + c * 8;
        if (first) {
            *reinterpret_cast<float4*>(dst)     = make_float4(acc[0], acc[1], acc[2], acc[3]);
            *reinterpret_cast<float4*>(dst + 4) = make_float4(acc[4], acc[5], acc[6], acc[7]);
            if (c == 0) denom[n] = ds;
        } else {
            float4 o0 = *reinterpret_cast<const float4*>(dst);
            float4 o1 = *reinterpret_cast<const float4*>(dst + 4);
            o0.x += acc[0]; o0.y += acc[1]; o0.z += acc[2]; o0.w += acc[3];
            o1.x += acc[4]; o1.y += acc[5]; o1.z += acc[6]; o1.w += acc[7];
            *reinterpret_cast<float4*>(dst) = o0;
            *reinterpret_cast<float4*>(dst + 4) = o1;
            if (c == 0) denom[n] += ds;
        }
    }
}

// ---------------- normalize: out /= denom[node] ---------------------------
__global__ void normalize_kernel(float* __restrict__ out, const float* __restrict__ denom) {
    int i = blockIdx.x * blockDim.x + threadIdx.x;   // one float4 each
    if (i >= NN * 128 / 4) return;
    int node = (i * 4) >> 7;
    float d = denom[node];
    float inv = d > 0.f ? 1.0f / d : 0.f;
    float4* o = reinterpret_cast<float4*>(out) + i;
    float4 v = *o;
    v.x *= inv; v.y *= inv; v.z *= inv; v.w *= inv;
    *o = v;
}

extern "C" void kernel_launch(void* const* d_in, const int* in_sizes, int n_in,
                              void* d_out, int out_size, void* d_ws, size_t ws_size,
                              hipStream_t stream) {
    const float* nodes = (const float*)d_in[0];
    const float* edges = (const float*)d_in[1];
    const int*   eidx  = (const int*)d_in[2];     // row0 = sender, row1 = receiver
    const float* Wq = (const float*)d_in[3];
    const float* bq = (const float*)d_in[4];
    const float* Wk = (const float*)d_in[5];
    const float* bk = (const float*)d_in[6];
    const float* Wv = (const float*)d_in[7];
    const float* bv = (const float*)d_in[8];
    const int* sidx = eidx;
    const int* ridx = eidx + NE;

    // workspace layout (16B aligned):
    char* ws = (char*)d_ws;
    unsigned short* wq_bf = (unsigned short*)ws;          // Wq||Wk stacked, then Wv
    unsigned short* wv_bf = wq_bf + 65536;
    unsigned short* q_bf  = (unsigned short*)(ws + 163840);
    unsigned short* k_bf  = q_bf + (size_t)NN * 128;
    char* ws2 = ws + 163840 + 2 * (size_t)NN * 128 * 2;   // after q,k (25.6 MB)
    int*   cnt   = (int*)ws2;                             // NCH*NN
    int*   offs  = cnt + NCH * NN;                        // NCH*NN (cursor)
    int*   offs2 = offs + NCH * NN;                       // NCH*(NN+1) pristine CSR
    int*   perm  = offs2 + NCH * (NN + 1) + 3;            // NE (local ids per chunk)
    unsigned short* vbuf = (unsigned short*)(perm + NE);  // CHUNK*128 bf16 (82 MB, reused)
    float* denom = (float*)(vbuf + (size_t)CHUNK * 128);  // NN
    float* out = (float*)d_out;

    init_cnt<<<(NCH * NN + 255) / 256, 256, 0, stream>>>(cnt);
    cast_w_kernel<<<320, 256, 0, stream>>>(Wq, Wk, Wv, wq_bf);
    hist5<<<(NE + 255) / 256, 256, 0, stream>>>(ridx, cnt);
    scan5<<<NCH, 1024, 0, stream>>>(cnt, offs, offs2);
    scatter5<<<(NE + 255) / 256, 256, 0, stream>>>(ridx, offs, perm);
    proj_qk<<<(NN + 63) / 64, 256, 0, stream>>>(nodes, wq_bf, bq, bk, q_bf, k_bf, NN);

    for (int c = 0; c < NCH; ++c) {
        v_chunk<<<CBLK, 512, 0, stream>>>(edges + (size_t)c * CHUNK * 128, wv_bf, bv, vbuf);
        gather_chunk<<<NN / 4, 256, 0, stream>>>(vbuf, perm + (size_t)c * CHUNK,
                                                 sidx + (size_t)c * CHUNK,
                                                 q_bf, k_bf,
                                                 offs2 + (size_t)c * (NN + 1),
                                                 out, denom, c == 0 ? 1 : 0);
    }
    normalize_kernel<<<(NN * 128 / 4 + 255) / 256, 256, 0, stream>>>(out, denom);
}